// Round 4
// baseline (3035.121 us; speedup 1.0000x reference)
//
#include <hip/hip_runtime.h>
#include <math.h>

// GRU_32564442038643 — round 4.
//  R3 post-mortem: 6010 cyc/step at 1 wave/SIMD = VALU/trans work (~2430) + ~3000 cyc of
//  unhidden latency (no TLP). Fix: M=32 per WG (two 16-row batch groups share the SAME
//  96 register-resident weight frags) -> independent work fills the stalls; X staged via
//  LDS ring with global_load_lds (frees 24 VGPRs, prefetch distance 1 step); z-gate moved
//  to phase B (az carried in regs, no zf). xgemm rewritten with register-resident weights
//  (was L2-streaming ~3.2 TB) -> HBM-bound ~60 us.

#define BATCH  256
#define SEQ    512
#define INPUT  256
#define HIDDEN 256
#define DTOT   512
#define NT     48
#define NT_O   16
#define LOG2E  1.44269504088896f

typedef float          f32x4 __attribute__((ext_vector_type(4)));
typedef short          s16x8 __attribute__((ext_vector_type(8)));
typedef unsigned short u16x8 __attribute__((ext_vector_type(8)));
typedef unsigned int   u32x2 __attribute__((ext_vector_type(2)));

// ws layout (bytes)
#define WH_OFF   0u            // 393216: h-part of [Wr|Wz|Wh], frag-packed bf16 (exp2-scaled)
#define WX_OFF   393216u       // 393216: x-part, wave-blocked frag layout (exp2-scaled)
#define WO_OFF   786432u       // 131072: Wo (unscaled)
#define X_OFF    917504u       // 201326592: X = x@Wx + b, bf16, wave-blocked frag layout
#define WS_NEED     (917504ull + 201326592ull)
#define WS_NEED_OLD 786432ull

__device__ __forceinline__ unsigned short f2bf(float f) {        // RNE
    unsigned int u = __float_as_uint(f);
    u += 0x7FFFu + ((u >> 16) & 1u);
    return (unsigned short)(u >> 16);
}
__device__ __forceinline__ unsigned short f2bf_fast(float f) {
    return (unsigned short)((__float_as_uint(f) + 0x8000u) >> 16);
}
__device__ __forceinline__ float bf2f(unsigned short u) {
    return __uint_as_float(((unsigned int)u) << 16);
}
__device__ __forceinline__ f32x4 cvt4(u32x2 u) {
    f32x4 a;
    a[0] = __uint_as_float(u[0] << 16);
    a[1] = __uint_as_float(u[0] & 0xffff0000u);
    a[2] = __uint_as_float(u[1] << 16);
    a[3] = __uint_as_float(u[1] & 0xffff0000u);
    return a;
}
__device__ __forceinline__ unsigned int pk2bf(float a, float b) { // [b|a] packed bf16
    return ((__float_as_uint(a) + 0x8000u) >> 16) |
           ((__float_as_uint(b) + 0x8000u) & 0xFFFF0000u);
}
#if __has_builtin(__builtin_amdgcn_exp2f)
#define EXP2F(x) __builtin_amdgcn_exp2f(x)
#else
#define EXP2F(x) exp2f(x)
#endif
#if __has_builtin(__builtin_amdgcn_rcpf)
#define RCPF(x) __builtin_amdgcn_rcpf(x)
#else
#define RCPF(x) (1.0f / (x))
#endif

// async global->LDS, 16 B per lane: gptr per-lane, lptr wave-uniform base.
__device__ __forceinline__ void async_ld16(const void* g, void* l) {
    __builtin_amdgcn_global_load_lds(
        (const __attribute__((address_space(1))) unsigned int*)g,
        (__attribute__((address_space(3))) unsigned int*)l, 16, 0, 0);
}

// ---------------- weight packing ----------------
// WH frag (kt,nt<48), lane l: 8 bf16 = W[k=256+kt*32+quad*8+j][n=nt*16+lan], gate=n>>8.
// WX wave-blocked: idx ((w*12+fi)*8+kt), fi=j*4+i -> gate j, col=(4w+i)*16+lan, k=kt*32+quad*8+j.
// WO frag (kt,nt<16) as R3.
__global__ __launch_bounds__(256) void pack_weights_k(
    const float* __restrict__ Wr, const float* __restrict__ Wz,
    const float* __restrict__ Wh, const float* __restrict__ Wo,
    unsigned short* __restrict__ ws)
{
    int tid = blockIdx.x * 256 + threadIdx.x;   // 0..57343 (896 tiles)
    int tile = tid >> 6;
    int l = tid & 63, quad = l >> 4, lan = l & 15;
    u16x8 v;
    unsigned short* dst;
    if (tile < 384) {                           // WH
        int kt = tile / NT, nt = tile % NT;
        int n = nt * 16 + lan, gate = n >> 8, col = n & 255;
        const float* W = gate == 0 ? Wr : (gate == 1 ? Wz : Wh);
        float scale = (gate == 2) ? 2.f * LOG2E : LOG2E;
        int kbase = 256 + kt * 32 + quad * 8;
        #pragma unroll
        for (int j = 0; j < 8; ++j) v[j] = f2bf(W[(kbase + j) * 256 + col] * scale);
        dst = (unsigned short*)((char*)ws + WH_OFF) + (size_t)(tile * 64 + l) * 8;
    } else if (tile < 768) {                    // WX (wave-blocked)
        int t2 = tile - 384;                    // = (w*12+fi)*8 + kt
        int kt = t2 & 7, q2 = t2 >> 3;
        int fi = q2 % 12, w = q2 / 12;
        int j2 = fi >> 2, i = fi & 3;
        const float* W = j2 == 0 ? Wr : (j2 == 1 ? Wz : Wh);
        float scale = (j2 == 2) ? 2.f * LOG2E : LOG2E;
        int col = (4 * w + i) * 16 + lan;
        int kbase = kt * 32 + quad * 8;
        #pragma unroll
        for (int j = 0; j < 8; ++j) v[j] = f2bf(W[(kbase + j) * 256 + col] * scale);
        dst = (unsigned short*)((char*)ws + WX_OFF) + (size_t)(t2 * 64 + l) * 8;
    } else {                                    // WO
        int t2 = tile - 768;
        int kt = t2 / NT_O, nt = t2 % NT_O;
        int col = nt * 16 + lan;
        int kbase = kt * 32 + quad * 8;
        #pragma unroll
        for (int j = 0; j < 8; ++j) v[j] = f2bf(Wo[(kbase + j) * 256 + col]);
        dst = (unsigned short*)((char*)ws + WO_OFF) + (size_t)(t2 * 64 + l) * 8;
    }
    *(u16x8*)dst = v;
}

// ---------------- X precompute: register-resident Wx ----------------
// 256 WGs x 256 thr (1 wave/SIMD). Wave w holds 96 Wx frags (384 VGPR) for its 12 nt.
// 32 units (t,gg) per WG; x_t staged f32 via global_load_lds, double-buffered.
__global__ __launch_bounds__(256, 1) void xgemm_k(
    const float* __restrict__ x,
    const float* __restrict__ br, const float* __restrict__ bz, const float* __restrict__ bh,
    unsigned short* __restrict__ ws)
{
    __shared__ __align__(16) float Xf[2][16][260];
    const int th = threadIdx.x, wave = th >> 6, l = th & 63, quad = l >> 4, lan = l & 15;
    const s16x8* WX = (const s16x8*)((char*)ws + WX_OFF);
    s16x8 wx[12][8];
    #pragma unroll
    for (int fi = 0; fi < 12; ++fi)
        #pragma unroll
        for (int kt = 0; kt < 8; ++kt) wx[fi][kt] = WX[(((size_t)wave * 12 + fi) * 8 + kt) * 64 + l];
    float bias[12];
    #pragma unroll
    for (int j = 0; j < 3; ++j) {
        const float* bb = j == 0 ? br : (j == 1 ? bz : bh);
        float sc = (j == 2) ? 2.f * LOG2E : LOG2E;
        #pragma unroll
        for (int i = 0; i < 4; ++i) bias[j * 4 + i] = bb[(4 * wave + i) * 16 + lan] * sc;
    }
    u32x2* Xout = (u32x2*)((char*)ws + X_OFF);

    // prime unit 0 -> buf 0
    {
        int unit = blockIdx.x * 32, t = unit >> 4, gg = unit & 15;
        #pragma unroll
        for (int rr = 0; rr < 4; ++rr) {
            int row = rr * 4 + wave;
            const float* src = x + (((size_t)(gg * 16 + row)) * SEQ + t) * INPUT + l * 4;
            async_ld16(src, &Xf[0][row][0]);
        }
    }
    for (int uu = 0; uu < 32; ++uu) {
        __syncthreads();                         // drains staging loads for this buf
        if (uu + 1 < 32) {
            int unit = blockIdx.x * 32 + uu + 1, t = unit >> 4, gg = unit & 15;
            int nb = (uu + 1) & 1;
            #pragma unroll
            for (int rr = 0; rr < 4; ++rr) {
                int row = rr * 4 + wave;
                const float* src = x + (((size_t)(gg * 16 + row)) * SEQ + t) * INPUT + l * 4;
                async_ld16(src, &Xf[nb][row][0]);
            }
        }
        int buf = uu & 1;
        f32x4 acc[12];
        #pragma unroll
        for (int fi = 0; fi < 12; ++fi) { acc[fi][0] = bias[fi]; acc[fi][1] = bias[fi]; acc[fi][2] = bias[fi]; acc[fi][3] = bias[fi]; }
        #pragma unroll
        for (int kt = 0; kt < 8; ++kt) {
            f32x4 a0 = *(const f32x4*)&Xf[buf][lan][kt * 32 + quad * 8];
            f32x4 a1 = *(const f32x4*)&Xf[buf][lan][kt * 32 + quad * 8 + 4];
            u16x8 ap;
            ap[0] = f2bf_fast(a0[0]); ap[1] = f2bf_fast(a0[1]); ap[2] = f2bf_fast(a0[2]); ap[3] = f2bf_fast(a0[3]);
            ap[4] = f2bf_fast(a1[0]); ap[5] = f2bf_fast(a1[1]); ap[6] = f2bf_fast(a1[2]); ap[7] = f2bf_fast(a1[3]);
            s16x8 a = (s16x8)ap;
            #pragma unroll
            for (int fi = 0; fi < 12; ++fi)
                acc[fi] = __builtin_amdgcn_mfma_f32_16x16x32_bf16(a, wx[fi][kt], acc[fi], 0, 0, 0);
        }
        size_t unit = (size_t)blockIdx.x * 32 + uu;
        #pragma unroll
        for (int fi = 0; fi < 12; ++fi) {
            u32x2 p;
            p[0] = pk2bf(acc[fi][0], acc[fi][1]);
            p[1] = pk2bf(acc[fi][2], acc[fi][3]);
            Xout[((unit * 4 + wave) * 12 + fi) * 64 + l] = p;
        }
    }
}

// ---------------- recurrence: M=32 per WG ----------------
// 8 WGs x 256 thr (1 wave/SIMD). Two 16-row batch groups share the 96 resident weight
// frags. X staged through a 2-deep LDS ring (global_load_lds, distance-1 prefetch).
// Dynamic LDS: Hb 16896 | RHb 16896 | Xring 98304 = 132096 B.
__global__ __launch_bounds__(256, 1) void gru_rec_k(
    const float* __restrict__ bo,
    unsigned short* __restrict__ ws,
    float* __restrict__ out)
{
    extern __shared__ __align__(16) char smem[];
    unsigned short (*Hb)[264]  = (unsigned short (*)[264])smem;            // h bf16, 32 rows
    unsigned short (*RHb)[264] = (unsigned short (*)[264])(smem + 16896);  // r*h bf16
    char* Xr = smem + 33792;                                               // ring [2][2][4][6144]

    const int th = threadIdx.x, wave = th >> 6, l = th & 63, quad = l >> 4, lan = l & 15;
    const int b = blockIdx.x;
    const s16x8* WH = (const s16x8*)((char*)ws + WH_OFF);
    s16x8 wfr[4][8], wfz[4][8], wfc[4][8];                 // 96 frags = 384 regs (VGPR+AGPR)
    #pragma unroll
    for (int i = 0; i < 4; ++i) {
        int ntr = 4 * wave + i;
        #pragma unroll
        for (int kt = 0; kt < 8; ++kt) {
            wfr[i][kt] = WH[(kt * NT + ntr) * 64 + l];
            wfz[i][kt] = WH[(kt * NT + 16 + ntr) * 64 + l];
            wfc[i][kt] = WH[(kt * NT + 32 + ntr) * 64 + l];
        }
    }
    for (int idx = th; idx < 32 * 264; idx += 256) ((unsigned short*)Hb)[idx] = 0;
    float h[2][4][4];
    #pragma unroll
    for (int g = 0; g < 2; ++g)
        #pragma unroll
        for (int i = 0; i < 4; ++i)
            #pragma unroll
            for (int r = 0; r < 4; ++r) h[g][i][r] = 0.f;

    const char* Xg = (const char*)ws + X_OFF;
    // prime t=0 -> buf 0
    #pragma unroll
    for (int gi = 0; gi < 2; ++gi) {
        int gg = 2 * b + gi;
        const char* sb = Xg + ((((size_t)gg) * 4 + wave) * 12) * 512;
        char* db = Xr + gi * 24576 + wave * 6144;
        #pragma unroll
        for (int inst = 0; inst < 6; ++inst)
            async_ld16(sb + inst * 1024 + l * 16, db + inst * 1024);
    }
    __syncthreads();   // drains prime

    for (int t = 0; t < SEQ; ++t) {
        int buf = t & 1;
        int t1 = (t + 1 < SEQ) ? t + 1 : t;
        // prefetch t+1 into buf^1 (drained at the phase-A barrier — one phase of hiding)
        #pragma unroll
        for (int gi = 0; gi < 2; ++gi) {
            int gg = 2 * b + gi;
            const char* sb = Xg + (((((size_t)t1 * 16 + gg)) * 4 + wave) * 12) * 512;
            char* db = Xr + (buf ^ 1) * 49152 + gi * 24576 + wave * 6144;
            #pragma unroll
            for (int inst = 0; inst < 6; ++inst)
                async_ld16(sb + inst * 1024 + l * 16, db + inst * 1024);
        }
        const char* Xw = Xr + buf * 49152 + wave * 6144;

        // ---- phase A: r,z preacts for both groups; A = h ----
        f32x4 ar[2][4], az[2][4];
        #pragma unroll
        for (int g = 0; g < 2; ++g)
            #pragma unroll
            for (int i = 0; i < 4; ++i) {
                ar[g][i] = cvt4(*(const u32x2*)(Xw + g * 24576 + (size_t)i * 512 + l * 8));
                az[g][i] = cvt4(*(const u32x2*)(Xw + g * 24576 + (size_t)(4 + i) * 512 + l * 8));
            }
        #pragma unroll
        for (int g = 0; g < 2; ++g)
            #pragma unroll
            for (int kt = 0; kt < 8; ++kt) {
                s16x8 a = *(const s16x8*)&Hb[g * 16 + lan][kt * 32 + quad * 8];
                #pragma unroll
                for (int i = 0; i < 4; ++i) {
                    ar[g][i] = __builtin_amdgcn_mfma_f32_16x16x32_bf16(a, wfr[i][kt], ar[g][i], 0, 0, 0);
                    az[g][i] = __builtin_amdgcn_mfma_f32_16x16x32_bf16(a, wfz[i][kt], az[g][i], 0, 0, 0);
                }
            }
        #pragma unroll
        for (int g = 0; g < 2; ++g)
            #pragma unroll
            for (int i = 0; i < 4; ++i) {
                int col = (4 * wave + i) * 16 + lan;
                #pragma unroll
                for (int r = 0; r < 4; ++r) {
                    float rg = RCPF(1.f + EXP2F(-ar[g][i][r]));
                    RHb[g * 16 + quad * 4 + r][col] = f2bf_fast(rg * h[g][i][r]);
                }
            }
        __syncthreads();

        // ---- phase B: candidate; A = r*h. z applied here (az carried in regs) ----
        f32x4 ac[2][4];
        #pragma unroll
        for (int g = 0; g < 2; ++g)
            #pragma unroll
            for (int i = 0; i < 4; ++i)
                ac[g][i] = cvt4(*(const u32x2*)(Xw + g * 24576 + (size_t)(8 + i) * 512 + l * 8));
        #pragma unroll
        for (int g = 0; g < 2; ++g)
            #pragma unroll
            for (int kt = 0; kt < 8; ++kt) {
                s16x8 a = *(const s16x8*)&RHb[g * 16 + lan][kt * 32 + quad * 8];
                #pragma unroll
                for (int i = 0; i < 4; ++i)
                    ac[g][i] = __builtin_amdgcn_mfma_f32_16x16x32_bf16(a, wfc[i][kt], ac[g][i], 0, 0, 0);
            }
        #pragma unroll
        for (int g = 0; g < 2; ++g)
            #pragma unroll
            for (int i = 0; i < 4; ++i) {
                int col = (4 * wave + i) * 16 + lan;
                #pragma unroll
                for (int r = 0; r < 4; ++r) {
                    float zg = RCPF(1.f + EXP2F(-az[g][i][r]));
                    float e  = EXP2F(ac[g][i][r]);           // exp(2*preact)
                    float hc = (e - 1.f) * RCPF(e + 1.f);    // tanh
                    float hn = zg * (h[g][i][r] - hc) + hc;
                    h[g][i][r] = hn;
                    Hb[g * 16 + quad * 4 + r][col] = f2bf_fast(hn);
                }
            }
        __syncthreads();
    }

    // ---- epilogue: out = h_last @ Wo + bo ----
    const s16x8* WO = (const s16x8*)((char*)ws + WO_OFF);
    #pragma unroll
    for (int g = 0; g < 2; ++g)
        #pragma unroll
        for (int i = 0; i < 4; ++i) {
            int nt = 4 * wave + i;
            int col = nt * 16 + lan;
            float bv = bo[col];
            f32x4 acc;
            acc[0] = bv; acc[1] = bv; acc[2] = bv; acc[3] = bv;
            #pragma unroll
            for (int kt = 0; kt < 8; ++kt) {
                s16x8 a = *(const s16x8*)&Hb[g * 16 + lan][kt * 32 + quad * 8];
                acc = __builtin_amdgcn_mfma_f32_16x16x32_bf16(a, WO[(kt * NT_O + nt) * 64 + l], acc, 0, 0, 0);
            }
            #pragma unroll
            for (int r = 0; r < 4; ++r)
                out[(size_t)((2 * b + g) * 16 + quad * 4 + r) * 256 + col] = acc[r];
        }
}

// ---------------- fallbacks (ws too small) ----------------
__global__ __launch_bounds__(256) void prep_weights_k(
    const float* __restrict__ Wr, const float* __restrict__ Wz,
    const float* __restrict__ Wh, unsigned short* __restrict__ W16)
{
    const int n = DTOT * HIDDEN;
    int idx = blockIdx.x * 256 + threadIdx.x;
    if (idx >= 3 * n) return;
    int m = idx / n;
    int r = idx - m * n;
    const float* src = (m == 0) ? Wr : ((m == 1) ? Wz : Wh);
    W16[idx] = f2bf(src[r]);
}
__device__ __forceinline__ float ldw(const unsigned short* p) { return bf2f(*p); }
__device__ __forceinline__ float ldw(const float* p)          { return *p; }

template <typename WT>
__global__ __launch_bounds__(256) void gru_seq_k(
    const float* __restrict__ x,
    const WT* __restrict__ Wr, const WT* __restrict__ Wz, const WT* __restrict__ Wh,
    const float* __restrict__ br, const float* __restrict__ bz, const float* __restrict__ bh,
    const float* __restrict__ Wo, const float* __restrict__ bo,
    float* __restrict__ out)
{
    const int b = blockIdx.x, j = threadIdx.x;
    __shared__ float xh[DTOT];
    __shared__ float xrh[DTOT];
    xh[INPUT + j] = 0.0f;
    const float brj = br[j], bzj = bz[j], bhj = bh[j];
    const float* xb = x + (size_t)b * SEQ * INPUT;
    const WT* wrj = Wr + j;
    const WT* wzj = Wz + j;
    const WT* whj = Wh + j;
    __syncthreads();
    for (int t = 0; t < SEQ; ++t) {
        float xv = xb[t * INPUT + j];
        xh[j] = xv; xrh[j] = xv;
        __syncthreads();
        float ar = brj, az = bzj;
        #pragma unroll 8
        for (int k = 0; k < DTOT; ++k) {
            float v = xh[k];
            ar += v * ldw(wrj + k * HIDDEN);
            az += v * ldw(wzj + k * HIDDEN);
        }
        float rg = 1.0f / (1.0f + __expf(-ar));
        float zg = 1.0f / (1.0f + __expf(-az));
        float hj = xh[INPUT + j];
        xrh[INPUT + j] = rg * hj;
        __syncthreads();
        float ah = bhj;
        #pragma unroll 8
        for (int k = 0; k < DTOT; ++k) ah += xrh[k] * ldw(whj + k * HIDDEN);
        float hc = tanhf(ah);
        float hn = zg * hj + (1.0f - zg) * hc;
        xh[INPUT + j] = hn;
        __syncthreads();
    }
    float acc = bo[j];
    #pragma unroll 8
    for (int k = 0; k < HIDDEN; ++k) acc += xh[INPUT + k] * Wo[k * HIDDEN + j];
    out[(size_t)b * HIDDEN + j] = acc;
}

extern "C" void kernel_launch(void* const* d_in, const int* in_sizes, int n_in,
                              void* d_out, int out_size, void* d_ws, size_t ws_size,
                              hipStream_t stream) {
    const float* x  = (const float*)d_in[0];
    const float* Wr = (const float*)d_in[1];
    const float* br = (const float*)d_in[2];
    const float* Wz = (const float*)d_in[3];
    const float* bz = (const float*)d_in[4];
    const float* Wh = (const float*)d_in[5];
    const float* bh = (const float*)d_in[6];
    const float* Wo = (const float*)d_in[7];
    const float* bo = (const float*)d_in[8];
    float* out = (float*)d_out;

    if (ws_size >= WS_NEED) {
        unsigned short* ws = (unsigned short*)d_ws;
        (void)hipFuncSetAttribute((const void*)gru_rec_k,
                                  hipFuncAttributeMaxDynamicSharedMemorySize, 132096);
        pack_weights_k<<<224, 256, 0, stream>>>(Wr, Wz, Wh, Wo, ws);
        xgemm_k<<<256, 256, 0, stream>>>(x, br, bz, bh, ws);
        gru_rec_k<<<8, 256, 132096, stream>>>(bo, ws, out);
    } else if (ws_size >= WS_NEED_OLD) {
        unsigned short* W16 = (unsigned short*)d_ws;
        const size_t n = (size_t)DTOT * HIDDEN;
        prep_weights_k<<<(int)((3 * n + 255) / 256), 256, 0, stream>>>(Wr, Wz, Wh, W16);
        gru_seq_k<unsigned short><<<BATCH, 256, 0, stream>>>(
            x, W16, W16 + n, W16 + 2 * n, br, bz, bh, Wo, bo, out);
    } else {
        gru_seq_k<float><<<BATCH, 256, 0, stream>>>(
            x, Wr, Wz, Wh, br, bz, bh, Wo, bo, out);
    }
}

// Round 5
// 1058.603 us; speedup vs baseline: 2.8671x; 2.8671x over previous
//
#include <hip/hip_runtime.h>
#include <math.h>

// GRU_32564442038643 — round 5.
//  R4 post-mortem: M=32 halved active CUs (8 WGs) and blew the phase-A register
//  budget; global_load_lds prefetch was drained at every barrier. Revert to M=16,
//  16 WGs, but with 512 thr = 8 waves (2 waves/SIMD) for TLP: each wave owns 6
//  column-tiles (r,z,cand of the SAME 32 cols) -> 48 weight frags = 192 regs/lane,
//  fits the 256-reg budget at 2 waves/SIMD; z and h carried in registers (R3).
//  X staged through a 2-deep LDS ring; prefetch issued at step top, drained at the
//  phase-A barrier (one phase of hiding; SIMD-partner wave fills the wait).

#define BATCH  256
#define SEQ    512
#define INPUT  256
#define HIDDEN 256
#define DTOT   512
#define NTC    48     // canonical column-tiles over N=768: ntc=6w+s, s:{0,1}=r,{2,3}=z,{4,5}=c, cols (2w+(s&1))*16..
#define NT_O   16
#define LOG2E  1.44269504088896f

typedef float          f32x4 __attribute__((ext_vector_type(4)));
typedef short          s16x8 __attribute__((ext_vector_type(8)));
typedef unsigned short u16x8 __attribute__((ext_vector_type(8)));
typedef unsigned int   u32x2 __attribute__((ext_vector_type(2)));

// ws layout (bytes)
#define WH_OFF   0u            // 393216: h-part weights, ntc frag order, exp2-scaled bf16
#define WX_OFF   393216u       // 393216: x-part, same order
#define WO_OFF   786432u       // 131072: Wo
#define X_OFF    917504u       // 201326592: X[unit][ntc][lane] u32x2, unit = t*16+g
#define WS_NEED     (917504ull + 201326592ull)
#define WS_NEED_OLD 786432ull

__device__ __forceinline__ unsigned short f2bf(float f) {        // RNE
    unsigned int u = __float_as_uint(f);
    u += 0x7FFFu + ((u >> 16) & 1u);
    return (unsigned short)(u >> 16);
}
__device__ __forceinline__ unsigned short f2bf_fast(float f) {
    return (unsigned short)((__float_as_uint(f) + 0x8000u) >> 16);
}
__device__ __forceinline__ float bf2f(unsigned short u) {
    return __uint_as_float(((unsigned int)u) << 16);
}
__device__ __forceinline__ f32x4 cvt4(u32x2 u) {
    f32x4 a;
    a[0] = __uint_as_float(u[0] << 16);
    a[1] = __uint_as_float(u[0] & 0xffff0000u);
    a[2] = __uint_as_float(u[1] << 16);
    a[3] = __uint_as_float(u[1] & 0xffff0000u);
    return a;
}
__device__ __forceinline__ unsigned int pk2bf(float a, float b) {
    return ((__float_as_uint(a) + 0x8000u) >> 16) |
           ((__float_as_uint(b) + 0x8000u) & 0xFFFF0000u);
}
#if __has_builtin(__builtin_amdgcn_exp2f)
#define EXP2F(x) __builtin_amdgcn_exp2f(x)
#else
#define EXP2F(x) exp2f(x)
#endif
#if __has_builtin(__builtin_amdgcn_rcpf)
#define RCPF(x) __builtin_amdgcn_rcpf(x)
#else
#define RCPF(x) (1.0f / (x))
#endif

__device__ __forceinline__ void async_ld16(const void* g, void* l) {
    __builtin_amdgcn_global_load_lds(
        (const __attribute__((address_space(1))) unsigned int*)g,
        (__attribute__((address_space(3))) unsigned int*)l, 16, 0, 0);
}

// ntc -> (gate, col-base)
__device__ __forceinline__ void ntc_decode(int ntc, int& gate, int& colbase) {
    int w = ntc / 6, s = ntc - 6 * w;
    gate = s >> 1;
    colbase = (2 * w + (s & 1)) * 16;
}

// ---------------- weight packing ----------------
// WH/WX frag (ntc,kt), lane l: 8 bf16 = W[k0 + kt*32 + quad*8 + j][colbase + lan]
__global__ __launch_bounds__(256) void pack_weights_k(
    const float* __restrict__ Wr, const float* __restrict__ Wz,
    const float* __restrict__ Wh, const float* __restrict__ Wo,
    unsigned short* __restrict__ ws)
{
    int tid = blockIdx.x * 256 + threadIdx.x;   // 896 tiles * 64
    int tile = tid >> 6;
    int l = tid & 63, quad = l >> 4, lan = l & 15;
    u16x8 v;
    unsigned short* dst;
    if (tile < 768) {
        int isH = tile < 384;
        int t2 = isH ? tile : tile - 384;       // = ntc*8 + kt
        int ntc = t2 >> 3, kt = t2 & 7;
        int gate, colbase;
        ntc_decode(ntc, gate, colbase);
        const float* W = gate == 0 ? Wr : (gate == 1 ? Wz : Wh);
        float scale = (gate == 2) ? 2.f * LOG2E : LOG2E;
        int col = colbase + lan;
        int kbase = (isH ? 256 : 0) + kt * 32 + quad * 8;
        #pragma unroll
        for (int j = 0; j < 8; ++j) v[j] = f2bf(W[(kbase + j) * 256 + col] * scale);
        dst = (unsigned short*)((char*)ws + (isH ? WH_OFF : WX_OFF)) + (size_t)(t2 * 64 + l) * 8;
    } else {
        int t2 = tile - 768;                    // = kt*16 + nt_o
        int kt = t2 / NT_O, nt = t2 % NT_O;
        int col = nt * 16 + lan;
        int kbase = kt * 32 + quad * 8;
        #pragma unroll
        for (int j = 0; j < 8; ++j) v[j] = f2bf(Wo[(kbase + j) * 256 + col]);
        dst = (unsigned short*)((char*)ws + WO_OFF) + (size_t)(t2 * 64 + l) * 8;
    }
    *(u16x8*)dst = v;
}

// ---------------- X precompute (R4 structure, new layout) ----------------
// 256 WGs x 256 thr (1 wave/SIMD). Wave v holds 96 Wx frags (ntc 12v..12v+11).
__global__ __launch_bounds__(256, 1) void xgemm_k(
    const float* __restrict__ x,
    const float* __restrict__ br, const float* __restrict__ bz, const float* __restrict__ bh,
    unsigned short* __restrict__ ws)
{
    __shared__ __align__(16) float Xf[2][16][260];   // pad 4: row stride 1040B, async per-row OK
    const int th = threadIdx.x, wave = th >> 6, l = th & 63, quad = l >> 4, lan = l & 15;
    const s16x8* WX = (const s16x8*)((char*)ws + WX_OFF);
    s16x8 wx[12][8];
    #pragma unroll
    for (int fi = 0; fi < 12; ++fi)
        #pragma unroll
        for (int kt = 0; kt < 8; ++kt)
            wx[fi][kt] = WX[(((size_t)(12 * wave + fi)) * 8 + kt) * 64 + l];
    float bias[12];
    #pragma unroll
    for (int fi = 0; fi < 12; ++fi) {
        int gate, colbase;
        ntc_decode(12 * wave + fi, gate, colbase);
        const float* bb = gate == 0 ? br : (gate == 1 ? bz : bh);
        bias[fi] = bb[colbase + lan] * (gate == 2 ? 2.f * LOG2E : LOG2E);
    }
    u32x2* Xout = (u32x2*)((char*)ws + X_OFF);

    {   // prime unit 0 -> buf 0
        int unit = blockIdx.x * 32, t = unit >> 4, gg = unit & 15;
        #pragma unroll
        for (int rr = 0; rr < 4; ++rr) {
            int row = rr * 4 + wave;
            const float* src = x + (((size_t)(gg * 16 + row)) * SEQ + t) * INPUT + l * 4;
            async_ld16(src, &Xf[0][row][0]);
        }
    }
    for (int uu = 0; uu < 32; ++uu) {
        __syncthreads();                         // drains this buf's staging
        if (uu + 1 < 32) {
            int unit = blockIdx.x * 32 + uu + 1, t = unit >> 4, gg = unit & 15;
            int nb = (uu + 1) & 1;
            #pragma unroll
            for (int rr = 0; rr < 4; ++rr) {
                int row = rr * 4 + wave;
                const float* src = x + (((size_t)(gg * 16 + row)) * SEQ + t) * INPUT + l * 4;
                async_ld16(src, &Xf[nb][row][0]);
            }
        }
        int buf = uu & 1;
        f32x4 acc[12];
        #pragma unroll
        for (int fi = 0; fi < 12; ++fi) { acc[fi][0] = bias[fi]; acc[fi][1] = bias[fi]; acc[fi][2] = bias[fi]; acc[fi][3] = bias[fi]; }
        #pragma unroll
        for (int kt = 0; kt < 8; ++kt) {
            f32x4 a0 = *(const f32x4*)&Xf[buf][lan][kt * 32 + quad * 8];
            f32x4 a1 = *(const f32x4*)&Xf[buf][lan][kt * 32 + quad * 8 + 4];
            u16x8 ap;
            ap[0] = f2bf_fast(a0[0]); ap[1] = f2bf_fast(a0[1]); ap[2] = f2bf_fast(a0[2]); ap[3] = f2bf_fast(a0[3]);
            ap[4] = f2bf_fast(a1[0]); ap[5] = f2bf_fast(a1[1]); ap[6] = f2bf_fast(a1[2]); ap[7] = f2bf_fast(a1[3]);
            s16x8 a = (s16x8)ap;
            #pragma unroll
            for (int fi = 0; fi < 12; ++fi)
                acc[fi] = __builtin_amdgcn_mfma_f32_16x16x32_bf16(a, wx[fi][kt], acc[fi], 0, 0, 0);
        }
        size_t unit = (size_t)blockIdx.x * 32 + uu;
        #pragma unroll
        for (int fi = 0; fi < 12; ++fi) {
            u32x2 p;
            p[0] = pk2bf(acc[fi][0], acc[fi][1]);
            p[1] = pk2bf(acc[fi][2], acc[fi][3]);
            Xout[(unit * NTC + 12 * wave + fi) * 64 + l] = p;
        }
    }
}

// ---------------- recurrence: 16 WGs x 512 thr (2 waves/SIMD) ----------------
// Wave w owns ntc 6w..6w+5 (r,z,cand of cols 32w..32w+31): 48 frags = 192 regs.
// Dynamic LDS: Hb 8448 | RHb 8448 | Xring 2*8*3072 = 49152 -> 66048 B.
__global__ __launch_bounds__(512, 2) void gru_rec_k(
    const float* __restrict__ bo,
    unsigned short* __restrict__ ws,
    float* __restrict__ out)
{
    extern __shared__ __align__(16) char smem[];
    unsigned short (*Hb)[264]  = (unsigned short (*)[264])smem;
    unsigned short (*RHb)[264] = (unsigned short (*)[264])(smem + 8448);
    char* Xr = smem + 16896;                       // [2][8 waves][3072]

    const int th = threadIdx.x, wave = th >> 6, l = th & 63, quad = l >> 4, lan = l & 15;
    const int b = blockIdx.x;
    const s16x8* WH = (const s16x8*)((char*)ws + WH_OFF);
    s16x8 wfr[2][8], wfz[2][8], wfc[2][8];         // 48 frags = 192 regs
    #pragma unroll
    for (int i = 0; i < 2; ++i)
        #pragma unroll
        for (int kt = 0; kt < 8; ++kt) {
            wfr[i][kt] = WH[((6 * wave + i) * 8 + kt) * 64 + l];
            wfz[i][kt] = WH[((6 * wave + 2 + i) * 8 + kt) * 64 + l];
            wfc[i][kt] = WH[((6 * wave + 4 + i) * 8 + kt) * 64 + l];
        }
    for (int idx = th; idx < 16 * 264; idx += 512) ((unsigned short*)Hb)[idx] = 0;
    float h[2][4];
    #pragma unroll
    for (int i = 0; i < 2; ++i)
        #pragma unroll
        for (int r = 0; r < 4; ++r) h[i][r] = 0.f;

    const char* Xg = (const char*)ws + X_OFF;
    {   // prime t=0 -> buf 0
        const char* sb = Xg + (((size_t)b) * NTC + 6 * wave) * 512;
        char* db = Xr + wave * 3072;
        #pragma unroll
        for (int inst = 0; inst < 3; ++inst)
            async_ld16(sb + inst * 1024 + l * 16, db + inst * 1024);
    }
    __syncthreads();

    for (int t = 0; t < SEQ; ++t) {
        int buf = t & 1;
        {   // prefetch t+1 -> buf^1 (drained at phase-A barrier; partner wave covers)
            int t1 = (t + 1 < SEQ) ? t + 1 : t;
            const char* sb = Xg + (((size_t)(t1 * 16 + b)) * NTC + 6 * wave) * 512;
            char* db = Xr + (buf ^ 1) * 24576 + wave * 3072;
            #pragma unroll
            for (int inst = 0; inst < 3; ++inst)
                async_ld16(sb + inst * 1024 + l * 16, db + inst * 1024);
        }
        const char* Xw = Xr + buf * 24576 + wave * 3072;

        // ---- phase A: r,z preacts; A = h(prev) ----
        f32x4 ar[2], az[2];
        #pragma unroll
        for (int i = 0; i < 2; ++i) {
            ar[i] = cvt4(*(const u32x2*)(Xw + (size_t)i * 512 + l * 8));
            az[i] = cvt4(*(const u32x2*)(Xw + (size_t)(2 + i) * 512 + l * 8));
        }
        #pragma unroll
        for (int kt = 0; kt < 8; ++kt) {
            s16x8 a = *(const s16x8*)&Hb[lan][kt * 32 + quad * 8];
            #pragma unroll
            for (int i = 0; i < 2; ++i) {
                ar[i] = __builtin_amdgcn_mfma_f32_16x16x32_bf16(a, wfr[i][kt], ar[i], 0, 0, 0);
                az[i] = __builtin_amdgcn_mfma_f32_16x16x32_bf16(a, wfz[i][kt], az[i], 0, 0, 0);
            }
        }
        #pragma unroll
        for (int i = 0; i < 2; ++i) {
            int col = (2 * wave + i) * 16 + lan;
            #pragma unroll
            for (int r = 0; r < 4; ++r) {
                float rg = RCPF(1.f + EXP2F(-ar[i][r]));
                RHb[quad * 4 + r][col] = f2bf_fast(rg * h[i][r]);
            }
        }
        __syncthreads();

        // ---- phase B: candidate; A = r*h; z applied from regs ----
        f32x4 ac[2];
        #pragma unroll
        for (int i = 0; i < 2; ++i)
            ac[i] = cvt4(*(const u32x2*)(Xw + (size_t)(4 + i) * 512 + l * 8));
        #pragma unroll
        for (int kt = 0; kt < 8; ++kt) {
            s16x8 a = *(const s16x8*)&RHb[lan][kt * 32 + quad * 8];
            #pragma unroll
            for (int i = 0; i < 2; ++i)
                ac[i] = __builtin_amdgcn_mfma_f32_16x16x32_bf16(a, wfc[i][kt], ac[i], 0, 0, 0);
        }
        #pragma unroll
        for (int i = 0; i < 2; ++i) {
            int col = (2 * wave + i) * 16 + lan;
            #pragma unroll
            for (int r = 0; r < 4; ++r) {
                float zg = RCPF(1.f + EXP2F(-az[i][r]));
                float e  = EXP2F(ac[i][r]);              // exp(2*preact)
                float hc = (e - 1.f) * RCPF(e + 1.f);    // tanh
                float hn = zg * (h[i][r] - hc) + hc;
                h[i][r] = hn;
                Hb[quad * 4 + r][col] = f2bf_fast(hn);
            }
        }
        __syncthreads();
    }

    // ---- epilogue: out = h_last @ Wo + bo; wave w owns nt_o {2w, 2w+1} ----
    const s16x8* WO = (const s16x8*)((char*)ws + WO_OFF);
    #pragma unroll
    for (int i = 0; i < 2; ++i) {
        int nt = 2 * wave + i;
        int col = nt * 16 + lan;
        float bv = bo[col];
        f32x4 acc;
        acc[0] = bv; acc[1] = bv; acc[2] = bv; acc[3] = bv;
        #pragma unroll
        for (int kt = 0; kt < 8; ++kt) {
            s16x8 a = *(const s16x8*)&Hb[lan][kt * 32 + quad * 8];
            acc = __builtin_amdgcn_mfma_f32_16x16x32_bf16(a, WO[(kt * NT_O + nt) * 64 + l], acc, 0, 0, 0);
        }
        #pragma unroll
        for (int r = 0; r < 4; ++r)
            out[(size_t)(b * 16 + quad * 4 + r) * 256 + col] = acc[r];
    }
}

// ---------------- fallbacks (ws too small) ----------------
__global__ __launch_bounds__(256) void prep_weights_k(
    const float* __restrict__ Wr, const float* __restrict__ Wz,
    const float* __restrict__ Wh, unsigned short* __restrict__ W16)
{
    const int n = DTOT * HIDDEN;
    int idx = blockIdx.x * 256 + threadIdx.x;
    if (idx >= 3 * n) return;
    int m = idx / n;
    int r = idx - m * n;
    const float* src = (m == 0) ? Wr : ((m == 1) ? Wz : Wh);
    W16[idx] = f2bf(src[r]);
}
__device__ __forceinline__ float ldw(const unsigned short* p) { return bf2f(*p); }
__device__ __forceinline__ float ldw(const float* p)          { return *p; }

template <typename WT>
__global__ __launch_bounds__(256) void gru_seq_k(
    const float* __restrict__ x,
    const WT* __restrict__ Wr, const WT* __restrict__ Wz, const WT* __restrict__ Wh,
    const float* __restrict__ br, const float* __restrict__ bz, const float* __restrict__ bh,
    const float* __restrict__ Wo, const float* __restrict__ bo,
    float* __restrict__ out)
{
    const int b = blockIdx.x, j = threadIdx.x;
    __shared__ float xh[DTOT];
    __shared__ float xrh[DTOT];
    xh[INPUT + j] = 0.0f;
    const float brj = br[j], bzj = bz[j], bhj = bh[j];
    const float* xb = x + (size_t)b * SEQ * INPUT;
    const WT* wrj = Wr + j;
    const WT* wzj = Wz + j;
    const WT* whj = Wh + j;
    __syncthreads();
    for (int t = 0; t < SEQ; ++t) {
        float xv = xb[t * INPUT + j];
        xh[j] = xv; xrh[j] = xv;
        __syncthreads();
        float ar = brj, az = bzj;
        #pragma unroll 8
        for (int k = 0; k < DTOT; ++k) {
            float v = xh[k];
            ar += v * ldw(wrj + k * HIDDEN);
            az += v * ldw(wzj + k * HIDDEN);
        }
        float rg = 1.0f / (1.0f + __expf(-ar));
        float zg = 1.0f / (1.0f + __expf(-az));
        float hj = xh[INPUT + j];
        xrh[INPUT + j] = rg * hj;
        __syncthreads();
        float ah = bhj;
        #pragma unroll 8
        for (int k = 0; k < DTOT; ++k) ah += xrh[k] * ldw(whj + k * HIDDEN);
        float hc = tanhf(ah);
        float hn = zg * hj + (1.0f - zg) * hc;
        xh[INPUT + j] = hn;
        __syncthreads();
    }
    float acc = bo[j];
    #pragma unroll 8
    for (int k = 0; k < HIDDEN; ++k) acc += xh[INPUT + k] * Wo[k * HIDDEN + j];
    out[(size_t)b * HIDDEN + j] = acc;
}

extern "C" void kernel_launch(void* const* d_in, const int* in_sizes, int n_in,
                              void* d_out, int out_size, void* d_ws, size_t ws_size,
                              hipStream_t stream) {
    const float* x  = (const float*)d_in[0];
    const float* Wr = (const float*)d_in[1];
    const float* br = (const float*)d_in[2];
    const float* Wz = (const float*)d_in[3];
    const float* bz = (const float*)d_in[4];
    const float* Wh = (const float*)d_in[5];
    const float* bh = (const float*)d_in[6];
    const float* Wo = (const float*)d_in[7];
    const float* bo = (const float*)d_in[8];
    float* out = (float*)d_out;

    if (ws_size >= WS_NEED) {
        unsigned short* ws = (unsigned short*)d_ws;
        (void)hipFuncSetAttribute((const void*)gru_rec_k,
                                  hipFuncAttributeMaxDynamicSharedMemorySize, 66048);
        pack_weights_k<<<224, 256, 0, stream>>>(Wr, Wz, Wh, Wo, ws);
        xgemm_k<<<256, 256, 0, stream>>>(x, br, bz, bh, ws);
        gru_rec_k<<<16, 512, 66048, stream>>>(bo, ws, out);
    } else if (ws_size >= WS_NEED_OLD) {
        unsigned short* W16 = (unsigned short*)d_ws;
        const size_t n = (size_t)DTOT * HIDDEN;
        prep_weights_k<<<(int)((3 * n + 255) / 256), 256, 0, stream>>>(Wr, Wz, Wh, W16);
        gru_seq_k<unsigned short><<<BATCH, 256, 0, stream>>>(
            x, W16, W16 + n, W16 + 2 * n, br, bz, bh, Wo, bo, out);
    } else {
        gru_seq_k<float><<<BATCH, 256, 0, stream>>>(
            x, Wr, Wz, Wh, br, bz, bh, Wo, bo, out);
    }
}